// Round 6
// baseline (578.349 us; speedup 1.0000x reference)
//
#include <hip/hip_runtime.h>

// NaturalVariation: out = x + softmax(x@W_sel + b_sel)@patterns + EMA(0.05*noise)
// B=4, T=8192, H=1024, P=8. fp32 in/out.
//
// EMA truncation: 0.9^64 = 1.18e-3 -> worst-case dropped tail ~3e-4 << tol.
// Chunks are independent given a 64-step warm-up.
//
// R6 vs R5 (153us): R5's grid was 256 blocks = exactly 1 block/CU, so
// Part A (~55us latency-bound logits) and Part B (~95us streaming) ran
// SERIALLY per CU (Occ 41% = 16/32 waves). R6: CHUNK 64 -> grid 512 =
// 2 resident blocks/CU (VGPR pinned <=64 via __launch_bounds__(1024,8)),
// so one block's Part B overlaps the other's Part A. Part A now needs
// only waves 0-7 (8 tokens x 8 waves = 64-token chunk); waves 8-15 do
// warm-up then wait at the single barrier. Known cost (R2 measured):
// halving CHUNK leaks ~35MB warm re-reads to HBM (~+6us) -- accepted.

#define T_LEN 8192
#define H_DIM 1024
#define B_DIM 4
#define NPAT 8
#define CHUNK 64             // tokens per block
#define WARM 64              // EMA warm-up steps
#define NCHUNK (T_LEN / CHUNK)   // 128 chunks per batch row

static_assert(WARM <= CHUNK, "warm-up must stay within previous chunk");

// grid = B*NCHUNK = 512 blocks of 1024 threads -> 2 blocks/CU.
__global__ __launch_bounds__(1024, 8) void kF_fused(
    const float* __restrict__ x, const float* __restrict__ noise,
    const float* __restrict__ Wsel, const float* __restrict__ bsel,
    const float* __restrict__ patterns, float* __restrict__ out)
{
    __shared__ float wsm[CHUNK * NPAT];   // 2KB: chunk's softmax weights

    const int tid  = threadIdx.x;
    const int wave = tid >> 6;            // 0..15
    const int lane = tid & 63;
    const int b    = blockIdx.x >> 7;     // / NCHUNK (=128)
    const int c    = blockIdx.x & (NCHUNK - 1);
    const size_t tokbase = (size_t)b * T_LEN + c * CHUNK;
    const int h    = tid;                 // Part B column (0..1023)

    // ---- EMA warm-up (all waves): serial FMA chain, loads independent ----
    float s = 0.0f;
    const int nw = (c == 0) ? 0 : WARM;
    const float* nptr = noise + (tokbase - nw) * (size_t)H_DIM + h;
#pragma unroll 8
    for (int i = 0; i < nw; ++i) {
        s = fmaf(0.9f, s, 0.005f * (*nptr));
        nptr += H_DIM;
    }
    // nptr now points at noise[tokbase][h]

    float pat[NPAT];
#pragma unroll
    for (int p = 0; p < NPAT; ++p) pat[p] = patterns[p * H_DIM + h];

    // ================= Part A: chunk weights (waves 0-7 only) ===========
    // Wave w covers tokens tokbase + w*8 .. +7 (8 waves x 8 = 64 = CHUNK).
    if (wave < 8) {
        float a[64];
#pragma unroll
        for (int q = 0; q < 64; ++q) a[q] = 0.0f;

        const float* xw = x + (tokbase + (size_t)wave * 8) * H_DIM + lane;

#pragma unroll 2
        for (int r = 0; r < 16; ++r) {
            const int hh = r * 64 + lane;
            // W row: 8 floats at 32B lane stride -> 2KB span, fully used
            const float4 wa = *(const float4*)(Wsel + (size_t)hh * NPAT);
            const float4 wb = *(const float4*)(Wsel + (size_t)hh * NPAT + 4);
            float xv[8];
#pragma unroll
            for (int j = 0; j < 8; ++j)        // 256B/wave coalesced
                xv[j] = xw[(size_t)j * H_DIM + r * 64];
#pragma unroll
            for (int j = 0; j < 8; ++j) {
                a[j * 8 + 0] = fmaf(xv[j], wa.x, a[j * 8 + 0]);
                a[j * 8 + 1] = fmaf(xv[j], wa.y, a[j * 8 + 1]);
                a[j * 8 + 2] = fmaf(xv[j], wa.z, a[j * 8 + 2]);
                a[j * 8 + 3] = fmaf(xv[j], wa.w, a[j * 8 + 3]);
                a[j * 8 + 4] = fmaf(xv[j], wb.x, a[j * 8 + 4]);
                a[j * 8 + 5] = fmaf(xv[j], wb.y, a[j * 8 + 5]);
                a[j * 8 + 6] = fmaf(xv[j], wb.z, a[j * 8 + 6]);
                a[j * 8 + 7] = fmaf(xv[j], wb.w, a[j * 8 + 7]);
            }
        }

        // exchange-halves butterfly (R2-verified): after 6 steps, a[0] at
        // lane l = full logit sum for (token wave*8 + (l>>3), pattern l&7)
#pragma unroll
        for (int sp = 0; sp < 6; ++sp) {
            const int o = 1 << sp;
            const int half = 32 >> sp;
            const bool hib = (lane & o) != 0;
#pragma unroll
            for (int m = 0; m < half; ++m) {
                const float lo = a[2 * m];
                const float hi = a[2 * m + 1];
                const float disc = hib ? lo : hi;
                const float keep = hib ? hi : lo;
                a[m] = keep + __shfl_xor(disc, o, 64);
            }
        }

        const float logit = a[0] + bsel[lane & 7];   // TEMPERATURE == 1.0

        // softmax across the 8 lanes sharing a token (R2-verified)
        float mx = logit;
        mx = fmaxf(mx, __shfl_xor(mx, 1, 64));
        mx = fmaxf(mx, __shfl_xor(mx, 2, 64));
        mx = fmaxf(mx, __shfl_xor(mx, 4, 64));
        const float e = __expf(logit - mx);
        float den = e;
        den += __shfl_xor(den, 1, 64);
        den += __shfl_xor(den, 2, 64);
        den += __shfl_xor(den, 4, 64);

        // wsm[(w*8 + l>>3)*8 + (l&7)] == wsm[w*64 + l]: coalesced write
        wsm[wave * 64 + lane] = e / den;
    }

    __syncthreads();   // the ONLY barrier

    // ================= Part B: streaming fuse (R1-kB body) ==============
    const float* xptr = x + tokbase * H_DIM + h;
    float*       optr = out + tokbase * H_DIM + h;
#pragma unroll 8
    for (int i = 0; i < CHUNK; ++i) {
        const float nv = *nptr;
        const float xv = *xptr;
        s = fmaf(0.9f, s, 0.005f * nv);

        // uniform-address LDS reads (broadcast, conflict-free)
        const float4 wA = *(const float4*)(wsm + i * NPAT);
        const float4 wB = *(const float4*)(wsm + i * NPAT + 4);
        float v = 0.0f;
        v = fmaf(wA.x, pat[0], v);
        v = fmaf(wA.y, pat[1], v);
        v = fmaf(wA.z, pat[2], v);
        v = fmaf(wA.w, pat[3], v);
        v = fmaf(wB.x, pat[4], v);
        v = fmaf(wB.y, pat[5], v);
        v = fmaf(wB.z, pat[6], v);
        v = fmaf(wB.w, pat[7], v);

        *optr = xv + v + s;
        nptr += H_DIM; xptr += H_DIM; optr += H_DIM;
    }
}

extern "C" void kernel_launch(void* const* d_in, const int* in_sizes, int n_in,
                              void* d_out, int out_size, void* d_ws, size_t ws_size,
                              hipStream_t stream) {
    const float* x        = (const float*)d_in[0];  // [B,T,H]
    const float* Wsel     = (const float*)d_in[1];  // [H,8]
    const float* bsel     = (const float*)d_in[2];  // [8]
    const float* patterns = (const float*)d_in[3];  // [8,H]
    const float* noise    = (const float*)d_in[4];  // [B,T,H]
    float* out = (float*)d_out;
    (void)d_ws; (void)ws_size;

    kF_fused<<<B_DIM * NCHUNK, 1024, 0, stream>>>(x, noise, Wsel, bsel,
                                                  patterns, out);
}